// Round 2
// baseline (2252.577 us; speedup 1.0000x reference)
//
#include <hip/hip_runtime.h>

#define HID 128
#define ODIM 64

// ---------------------------------------------------------------------------
// Encode: x0[n][c] = relu(Win[color][c] + fr*Win[10][c] + fc*Win[11][c] + bin[c])
// (one-hot @ Win collapses to a row gather; matches np's fp32 add order:
//  color row first, then row-pos, then col-pos, then bias.)
// One float4 (4 channels) per thread; 32 threads per node.
// ---------------------------------------------------------------------------
__global__ __launch_bounds__(256) void k_encode(
    const int* __restrict__ grids, const float* __restrict__ Win,
    const float* __restrict__ binp, float* __restrict__ X, int b0, int nodes) {
  int t = blockIdx.x * 256 + threadIdx.x;
  if (t >= nodes * 32) return;
  int node = t >> 5;  // chunk-local node index
  int i = t & 31;     // float4 index within the 128-ch row
  int n = node % 900;
  int b = node / 900;
  int r = n / 30, c = n - r * 30;
  int color = grids[(b0 + b) * 900 + n];
  float fr = (float)r / 29.0f, fc = (float)c / 29.0f;
  float4 wc = ((const float4*)(Win + color * HID))[i];
  float4 wr = ((const float4*)(Win + 10 * HID))[i];
  float4 wl = ((const float4*)(Win + 11 * HID))[i];
  float4 bb = ((const float4*)binp)[i];
  float4 v;
  v.x = fmaxf(wc.x + fr * wr.x + fc * wl.x + bb.x, 0.0f);
  v.y = fmaxf(wc.y + fr * wr.y + fc * wl.y + bb.y, 0.0f);
  v.z = fmaxf(wc.z + fr * wr.z + fc * wl.z + bb.z, 0.0f);
  v.w = fmaxf(wc.w + fr * wr.w + fc * wl.w + bb.w, 0.0f);
  ((float4*)(X + (size_t)node * HID))[i] = v;
}

// ---------------------------------------------------------------------------
// fp32 GEMM: Hout[M, NOUT] = Xs[M, 128] @ W[128, NOUT] (+ bias).
// No fp32 MFMA on CDNA4 -> vector-ALU outer-product GEMM.
// Block = 256 threads, tile = ROWS x NOUT, 4x4 accumulator per thread.
// X tile staged once in LDS (stride 132 -> conflict-free); W staged in two
// K=64 halves (keeps LDS at ~49 KB -> 3 blocks/CU). Inner loop per k:
// 1x ds_read_b128 (W, consecutive) + 4x broadcast ds_read_b32 (X) + 16 FMA.
// ---------------------------------------------------------------------------
template <int NOUT, bool BIAS>
__global__ __launch_bounds__(256) void k_gemm(
    const float* __restrict__ Xs, const float* __restrict__ W,
    const float* __restrict__ bias, float* __restrict__ Hout, int nodesTotal) {
  constexpr int NT = NOUT / 4;      // thread col-groups (32 or 16)
  constexpr int MT = 256 / NT;      // thread row-groups (8 or 16)
  constexpr int ROWS = MT * 4;      // 32 or 64
  constexpr int XSTR = 132;         // padded X leading dim

  __shared__ float Wl[64 * NOUT];   // one K-half of W
  __shared__ float Xl[ROWS * XSTR];

  int t = threadIdx.x;
  int rowBase = blockIdx.x * ROWS;

  // stage X rows [rowBase, rowBase+ROWS), coalesced float4, clamp OOB rows
  for (int f = t; f < ROWS * 32; f += 256) {
    int row = f >> 5, c4 = f & 31;
    int gr = rowBase + row;
    if (gr > nodesTotal - 1) gr = nodesTotal - 1;
    float4 v = *(const float4*)(Xs + (size_t)gr * HID + c4 * 4);
    *(float4*)(Xl + row * XSTR + c4 * 4) = v;
  }

  int tx = t % NT;  // col group (4 cols)
  int ty = t / NT;  // row group (4 rows)

  float4 acc[4];
#pragma unroll
  for (int i = 0; i < 4; ++i) acc[i] = make_float4(0.f, 0.f, 0.f, 0.f);

  for (int kp = 0; kp < 2; ++kp) {
    __syncthreads();  // X ready (kp=0) / previous K-half consumed (kp=1)
    // stage W rows [kp*64, kp*64+64), contiguous copy
    {
      const float4* Wg4 = (const float4*)(W + kp * 64 * NOUT);
      float4* Wl4 = (float4*)Wl;
      for (int f = t; f < 16 * NOUT; f += 256) Wl4[f] = Wg4[f];
    }
    __syncthreads();

    const float* xr0 = Xl + (ty * 4 + 0) * XSTR + kp * 64;
    const float* xr1 = Xl + (ty * 4 + 1) * XSTR + kp * 64;
    const float* xr2 = Xl + (ty * 4 + 2) * XSTR + kp * 64;
    const float* xr3 = Xl + (ty * 4 + 3) * XSTR + kp * 64;
#pragma unroll 8
    for (int kk = 0; kk < 64; ++kk) {
      float4 wv = *(const float4*)(Wl + kk * NOUT + tx * 4);
      float x0 = xr0[kk], x1 = xr1[kk], x2 = xr2[kk], x3 = xr3[kk];
      acc[0].x = fmaf(x0, wv.x, acc[0].x);
      acc[0].y = fmaf(x0, wv.y, acc[0].y);
      acc[0].z = fmaf(x0, wv.z, acc[0].z);
      acc[0].w = fmaf(x0, wv.w, acc[0].w);
      acc[1].x = fmaf(x1, wv.x, acc[1].x);
      acc[1].y = fmaf(x1, wv.y, acc[1].y);
      acc[1].z = fmaf(x1, wv.z, acc[1].z);
      acc[1].w = fmaf(x1, wv.w, acc[1].w);
      acc[2].x = fmaf(x2, wv.x, acc[2].x);
      acc[2].y = fmaf(x2, wv.y, acc[2].y);
      acc[2].z = fmaf(x2, wv.z, acc[2].z);
      acc[2].w = fmaf(x2, wv.w, acc[2].w);
      acc[3].x = fmaf(x3, wv.x, acc[3].x);
      acc[3].y = fmaf(x3, wv.y, acc[3].y);
      acc[3].z = fmaf(x3, wv.z, acc[3].z);
      acc[3].w = fmaf(x3, wv.w, acc[3].w);
    }
  }

  float4 bv = make_float4(0.f, 0.f, 0.f, 0.f);
  if (BIAS) bv = *(const float4*)(bias + tx * 4);
#pragma unroll
  for (int i = 0; i < 4; ++i) {
    int gr = rowBase + ty * 4 + i;
    if (gr < nodesTotal) {
      float4 o;
      o.x = acc[i].x + bv.x;
      o.y = acc[i].y + bv.y;
      o.z = acc[i].z + bv.z;
      o.w = acc[i].w + bv.w;
      *(float4*)(Hout + (size_t)gr * NOUT + tx * 4) = o;
    }
  }
}

// ---------------------------------------------------------------------------
// Aggregation (5-point grid stencil w/ symmetric GCN norm) + bias + LayerNorm
// + relu + residual, in-place on X. One wave per node; lane owns 2 channels
// (float2). deg(r,c) = 1 + #adjacent (self-loop included). Two-pass variance.
// ---------------------------------------------------------------------------
__global__ __launch_bounds__(256) void k_aggln(
    const float* __restrict__ Hb, float* __restrict__ X,
    const float* __restrict__ bg, const float* __restrict__ gam,
    const float* __restrict__ bet, int nodesTotal) {
  int lane = threadIdx.x & 63;
  int node = blockIdx.x * 4 + (threadIdx.x >> 6);
  if (node >= nodesTotal) return;
  int n = node % 900;
  int r = n / 30, c = n - r * 30;
  float dc = rsqrtf((float)(1 + (r > 0) + (r < 29) + (c > 0) + (c < 29)));

  float a0 = 0.f, a1 = 0.f;
  float2 p;
  float w;
  // self (coef = dinv^2)
  p = ((const float2*)(Hb + (size_t)node * HID))[lane];
  w = dc * dc;
  a0 += w * p.x; a1 += w * p.y;
  if (r > 0) {  // up neighbor (r-1,c): deg = 2 + (r>1) + (c>0) + (c<29)
    float dn = rsqrtf((float)(2 + (r > 1) + (c > 0) + (c < 29)));
    p = ((const float2*)(Hb + (size_t)(node - 30) * HID))[lane];
    w = dc * dn; a0 += w * p.x; a1 += w * p.y;
  }
  if (r < 29) {  // down (r+1,c): deg = 2 + (r<28) + (c>0) + (c<29)
    float dn = rsqrtf((float)(2 + (r < 28) + (c > 0) + (c < 29)));
    p = ((const float2*)(Hb + (size_t)(node + 30) * HID))[lane];
    w = dc * dn; a0 += w * p.x; a1 += w * p.y;
  }
  if (c > 0) {  // left (r,c-1): deg = 2 + (r>0) + (r<29) + (c>1)
    float dn = rsqrtf((float)(2 + (r > 0) + (r < 29) + (c > 1)));
    p = ((const float2*)(Hb + (size_t)(node - 1) * HID))[lane];
    w = dc * dn; a0 += w * p.x; a1 += w * p.y;
  }
  if (c < 29) {  // right (r,c+1): deg = 2 + (r>0) + (r<29) + (c<28)
    float dn = rsqrtf((float)(2 + (r > 0) + (r < 29) + (c < 28)));
    p = ((const float2*)(Hb + (size_t)(node + 1) * HID))[lane];
    w = dc * dn; a0 += w * p.x; a1 += w * p.y;
  }
  float2 bp = ((const float2*)bg)[lane];
  float v0 = a0 + bp.x, v1 = a1 + bp.y;

  // two-pass mean/variance across 128 channels (64-lane butterfly)
  float s = v0 + v1;
#pragma unroll
  for (int off = 32; off > 0; off >>= 1) s += __shfl_xor(s, off, 64);
  float mean = s * (1.f / 128.f);
  float d0 = v0 - mean, d1 = v1 - mean;
  float ss = d0 * d0 + d1 * d1;
#pragma unroll
  for (int off = 32; off > 0; off >>= 1) ss += __shfl_xor(ss, off, 64);
  float rsd = rsqrtf(ss * (1.f / 128.f) + 1e-5f);

  float2 g = ((const float2*)gam)[lane];
  float2 bt = ((const float2*)bet)[lane];
  float y0 = fmaxf(d0 * rsd * g.x + bt.x, 0.f);
  float y1 = fmaxf(d1 * rsd * g.y + bt.y, 0.f);

  float2* xrow = (float2*)(X + (size_t)node * HID);
  float2 xo = xrow[lane];
  xo.x += y0;
  xo.y += y1;
  xrow[lane] = xo;
}

// ---------------------------------------------------------------------------
extern "C" void kernel_launch(void* const* d_in, const int* in_sizes, int n_in,
                              void* d_out, int out_size, void* d_ws, size_t ws_size,
                              hipStream_t stream) {
  const int* grids = (const int*)d_in[0];
  // d_in[1] = edge_index: unused — fixed 30x30 grid + self-loops; degrees/coef
  // computed analytically in k_aggln.
  const float* Win  = (const float*)d_in[2];
  const float* bin  = (const float*)d_in[3];
  const float* Wg   = (const float*)d_in[4];
  const float* bg   = (const float*)d_in[5];
  const float* gam  = (const float*)d_in[6];
  const float* bet  = (const float*)d_in[7];
  const float* Wout = (const float*)d_in[8];
  const float* bout = (const float*)d_in[9];
  float* Out = (float*)d_out;

  const int Btot = 512;
  // Per batch image we need X (900*128 f32) + H (900*128 f32) in workspace.
  const size_t perBatchBytes = (size_t)900 * HID * 4 * 2;
  int chunkB = (int)(ws_size / perBatchBytes);
  if (chunkB > Btot) chunkB = Btot;
  if (chunkB < 1) chunkB = 1;
  int nch = (Btot + chunkB - 1) / chunkB;

  float* Xb = (float*)d_ws;
  float* Hb = Xb + (size_t)chunkB * 900 * HID;

  for (int ci = 0; ci < nch; ++ci) {
    int b0 = ci * chunkB;
    int cb = Btot - b0;
    if (cb > chunkB) cb = chunkB;
    int nodes = cb * 900;

    k_encode<<<dim3((nodes * 32 + 255) / 256), dim3(256), 0, stream>>>(
        grids, Win, bin, Xb, b0, nodes);
    for (int l = 0; l < 4; ++l) {
      k_gemm<128, false><<<dim3((nodes + 31) / 32), dim3(256), 0, stream>>>(
          Xb, Wg + l * HID * HID, (const float*)nullptr, Hb, nodes);
      k_aggln<<<dim3((nodes + 3) / 4), dim3(256), 0, stream>>>(
          Hb, Xb, bg + l * HID, gam + l * HID, bet + l * HID, nodes);
    }
    k_gemm<64, true><<<dim3((nodes + 63) / 64), dim3(256), 0, stream>>>(
        Xb, Wout, bout, Out + (size_t)b0 * 900 * ODIM, nodes);
  }
}

// Round 3
// 1226.103 us; speedup vs baseline: 1.8372x; 1.8372x over previous
//
#include <hip/hip_runtime.h>

#define HID 128
#define ODIM 64

typedef _Float16 half8 __attribute__((ext_vector_type(8)));
typedef float f32x4 __attribute__((ext_vector_type(4)));

// ---------------------------------------------------------------------------
// Encode: x0[n][c] = relu(Win[color][c] + fr*Win[10][c] + fc*Win[11][c] + bin[c])
// ---------------------------------------------------------------------------
__global__ __launch_bounds__(256) void k_encode(
    const int* __restrict__ grids, const float* __restrict__ Win,
    const float* __restrict__ binp, float* __restrict__ X, int b0, int nodes) {
  int t = blockIdx.x * 256 + threadIdx.x;
  if (t >= nodes * 32) return;
  int node = t >> 5;
  int i = t & 31;
  int n = node % 900;
  int b = node / 900;
  int r = n / 30, c = n - r * 30;
  int color = grids[(b0 + b) * 900 + n];
  float fr = (float)r / 29.0f, fc = (float)c / 29.0f;
  f32x4 wc = ((const f32x4*)(Win + color * HID))[i];
  f32x4 wr = ((const f32x4*)(Win + 10 * HID))[i];
  f32x4 wl = ((const f32x4*)(Win + 11 * HID))[i];
  f32x4 bb = ((const f32x4*)binp)[i];
  f32x4 v = wc + fr * wr + fc * wl + bb;
#pragma unroll
  for (int j = 0; j < 4; ++j) v[j] = fmaxf(v[j], 0.0f);
  ((f32x4*)(X + (size_t)node * HID))[i] = v;
}

// ---------------------------------------------------------------------------
// Fused GCN layer: Xout = relu(LN((A·Xin)@W + bg)) + Xin
// (agg(X@W) == (A·X)@W by linearity of the GCN aggregation.)
//
// Block = 256 thr (4 waves), 128 rows/block; wave owns 32 rows (2 M-tiles).
// A-side: per-lane 5-point stencil (analytic sym-norm coefs) gathered straight
//   from global into fp32, split to f16 hi/lo fragments (x ~= hi + lo, error
//   2^-22; 3 MFMA products hi*hi + hi*lo + lo*hi).
// B-side: W split+transposed into LDS planes WT[n][k] stride 136 (16B-aligned,
//   <=2-way bank alias = free), ds_read_b128 per frag.
// Epilogue: bias + LN per row — C/D layout row = q*4+reg lives in one 16-lane
//   group -> shuffle reduce; y -> LDS tile (reusing the W region, post-barrier),
//   then coalesced residual-add + store.
// ---------------------------------------------------------------------------
__global__ __launch_bounds__(256, 2) void k_hidden(
    const float* __restrict__ Xin, float* __restrict__ Xout,
    const float* __restrict__ W, const float* __restrict__ bgp,
    const float* __restrict__ gamp, const float* __restrict__ betp,
    int nodesTotal) {
  __shared__ __attribute__((aligned(16))) char smem[69632];
  _Float16* WThi = (_Float16*)smem;            // [128][136]
  _Float16* WTlo = (_Float16*)(smem + 34816);  // [128][136]
  float* Yl = (float*)smem;                    // [128][132] (post-barrier reuse)

  const int t = threadIdx.x;
  for (int i = t; i < 128 * 128; i += 256) {
    int k = i >> 7, n = i & 127;
    float w = W[i];
    _Float16 h = (_Float16)w;
    _Float16 l = (_Float16)(w - (float)h);
    WThi[n * 136 + k] = h;
    WTlo[n * 136 + k] = l;
  }
  __syncthreads();

  const int lane = t & 63;
  const int wave = t >> 6;
  const int q = lane >> 4, l16 = lane & 15;
  const int blockRow0 = blockIdx.x * 128;
  const int waveRow0 = blockRow0 + wave * 32;

  // per-M-tile stencil offsets (bytes) + symmetric-norm weights
  int offs[2][5];
  float wts[2][5];
#pragma unroll
  for (int mt = 0; mt < 2; ++mt) {
    int nd = waveRow0 + mt * 16 + l16;
    if (nd > nodesTotal - 1) nd = nodesTotal - 1;
    int n = nd % 900;
    int r = n / 30, c = n - r * 30;
    float dc = rsqrtf((float)(1 + (r > 0) + (r < 29) + (c > 0) + (c < 29)));
    offs[mt][0] = nd * 512;
    wts[mt][0] = dc * dc;
    bool v = r > 0;
    offs[mt][1] = (v ? nd - 30 : nd) * 512;
    wts[mt][1] = v ? dc * rsqrtf((float)(2 + (r > 1) + (c > 0) + (c < 29))) : 0.f;
    v = r < 29;
    offs[mt][2] = (v ? nd + 30 : nd) * 512;
    wts[mt][2] = v ? dc * rsqrtf((float)(2 + (r < 28) + (c > 0) + (c < 29))) : 0.f;
    v = c > 0;
    offs[mt][3] = (v ? nd - 1 : nd) * 512;
    wts[mt][3] = v ? dc * rsqrtf((float)(2 + (r > 0) + (r < 29) + (c > 1))) : 0.f;
    v = c < 29;
    offs[mt][4] = (v ? nd + 1 : nd) * 512;
    wts[mt][4] = v ? dc * rsqrtf((float)(2 + (r > 0) + (r < 29) + (c < 28))) : 0.f;
  }

  f32x4 acc[2][8];
#pragma unroll
  for (int mt = 0; mt < 2; ++mt)
#pragma unroll
    for (int nt = 0; nt < 8; ++nt) acc[mt][nt] = (f32x4){0.f, 0.f, 0.f, 0.f};

  const char* Xb = (const char*)Xin;
  for (int kc = 0; kc < 4; ++kc) {
    const int kbB = kc * 128 + q * 32;  // byte offset within a 512B row
    half8 Ahi[2], Alo[2];
#pragma unroll
    for (int mt = 0; mt < 2; ++mt) {
      const char* p0 = Xb + offs[mt][0] + kbB;
      f32x4 s0 = wts[mt][0] * (*(const f32x4*)p0);
      f32x4 s1 = wts[mt][0] * (*(const f32x4*)(p0 + 16));
#pragma unroll
      for (int e = 1; e < 5; ++e) {
        const char* p = Xb + offs[mt][e] + kbB;
        f32x4 u0 = *(const f32x4*)p;
        f32x4 u1 = *(const f32x4*)(p + 16);
        float we = wts[mt][e];
        s0 += we * u0;
        s1 += we * u1;
      }
#pragma unroll
      for (int j = 0; j < 4; ++j) {
        _Float16 h0 = (_Float16)s0[j];
        Ahi[mt][j] = h0;
        Alo[mt][j] = (_Float16)(s0[j] - (float)h0);
        _Float16 h1 = (_Float16)s1[j];
        Ahi[mt][4 + j] = h1;
        Alo[mt][4 + j] = (_Float16)(s1[j] - (float)h1);
      }
    }
    const int kb = kc * 32 + q * 8;
#pragma unroll
    for (int nt = 0; nt < 8; ++nt) {
      half8 bhi = *(const half8*)(WThi + (nt * 16 + l16) * 136 + kb);
      half8 blo = *(const half8*)(WTlo + (nt * 16 + l16) * 136 + kb);
#pragma unroll
      for (int mt = 0; mt < 2; ++mt) {
        acc[mt][nt] = __builtin_amdgcn_mfma_f32_16x16x32_f16(Alo[mt], bhi, acc[mt][nt], 0, 0, 0);
        acc[mt][nt] = __builtin_amdgcn_mfma_f32_16x16x32_f16(Ahi[mt], blo, acc[mt][nt], 0, 0, 0);
        acc[mt][nt] = __builtin_amdgcn_mfma_f32_16x16x32_f16(Ahi[mt], bhi, acc[mt][nt], 0, 0, 0);
      }
    }
  }

  // ---- epilogue: bias + LN + relu -> Y(LDS), then residual + coalesced store
  float bgv[8], gv[8], btv[8];
#pragma unroll
  for (int nt = 0; nt < 8; ++nt) {
    int cl = nt * 16 + l16;
    bgv[nt] = bgp[cl];
    gv[nt] = gamp[cl];
    btv[nt] = betp[cl];
  }
  __syncthreads();  // all waves done reading W LDS; Yl may now overwrite it
#pragma unroll
  for (int mt = 0; mt < 2; ++mt) {
#pragma unroll
    for (int reg = 0; reg < 4; ++reg) {
      float rs = 0.f;
#pragma unroll
      for (int nt = 0; nt < 8; ++nt) {
        acc[mt][nt][reg] += bgv[nt];
        rs += acc[mt][nt][reg];
      }
      rs += __shfl_xor(rs, 1, 64);
      rs += __shfl_xor(rs, 2, 64);
      rs += __shfl_xor(rs, 4, 64);
      rs += __shfl_xor(rs, 8, 64);
      float mean = rs * (1.f / 128.f);
      float ss = 0.f;
#pragma unroll
      for (int nt = 0; nt < 8; ++nt) {
        float d = acc[mt][nt][reg] - mean;
        ss += d * d;
      }
      ss += __shfl_xor(ss, 1, 64);
      ss += __shfl_xor(ss, 2, 64);
      ss += __shfl_xor(ss, 4, 64);
      ss += __shfl_xor(ss, 8, 64);
      float rsd = rsqrtf(ss * (1.f / 128.f) + 1e-5f);
      int row = wave * 32 + mt * 16 + q * 4 + reg;  // block-local row
      float* yr = Yl + row * 132;
#pragma unroll
      for (int nt = 0; nt < 8; ++nt) {
        float y = (acc[mt][nt][reg] - mean) * rsd * gv[nt] + btv[nt];
        yr[nt * 16 + l16] = fmaxf(y, 0.f);
      }
    }
  }
  __syncthreads();
  for (int f = t; f < 128 * 32; f += 256) {
    int row = f >> 5, c4 = f & 31;
    int gr = blockRow0 + row;
    if (gr < nodesTotal) {
      f32x4 x = *(const f32x4*)(Xin + (size_t)gr * HID + c4 * 4);
      f32x4 y = *(const f32x4*)(Yl + row * 132 + c4 * 4);
      *(f32x4*)(Xout + (size_t)gr * HID + c4 * 4) = x + y;
    }
  }
}

// ---------------------------------------------------------------------------
// Head: Out = Xin @ Wout + bout  (f16x3 MFMA, no stencil/LN/residual)
// ---------------------------------------------------------------------------
__global__ __launch_bounds__(256, 2) void k_head(
    const float* __restrict__ Xin, float* __restrict__ Out,
    const float* __restrict__ W, const float* __restrict__ bp, int nodesTotal) {
  __shared__ __attribute__((aligned(16))) char smem[34816];
  _Float16* WThi = (_Float16*)smem;            // [64][136]
  _Float16* WTlo = (_Float16*)(smem + 17408);  // [64][136]
  float* Yl = (float*)smem;                    // [128][68] (post-barrier reuse)

  const int t = threadIdx.x;
  for (int i = t; i < 128 * 64; i += 256) {
    int k = i >> 6, n = i & 63;
    float w = W[i];
    _Float16 h = (_Float16)w;
    _Float16 l = (_Float16)(w - (float)h);
    WThi[n * 136 + k] = h;
    WTlo[n * 136 + k] = l;
  }
  __syncthreads();

  const int lane = t & 63;
  const int wave = t >> 6;
  const int q = lane >> 4, l16 = lane & 15;
  const int blockRow0 = blockIdx.x * 128;
  const int waveRow0 = blockRow0 + wave * 32;

  int offs[2];
#pragma unroll
  for (int mt = 0; mt < 2; ++mt) {
    int nd = waveRow0 + mt * 16 + l16;
    if (nd > nodesTotal - 1) nd = nodesTotal - 1;
    offs[mt] = nd * 512;
  }

  f32x4 acc[2][4];
#pragma unroll
  for (int mt = 0; mt < 2; ++mt)
#pragma unroll
    for (int nt = 0; nt < 4; ++nt) acc[mt][nt] = (f32x4){0.f, 0.f, 0.f, 0.f};

  const char* Xb = (const char*)Xin;
  for (int kc = 0; kc < 4; ++kc) {
    const int kbB = kc * 128 + q * 32;
    half8 Ahi[2], Alo[2];
#pragma unroll
    for (int mt = 0; mt < 2; ++mt) {
      const char* p = Xb + offs[mt] + kbB;
      f32x4 s0 = *(const f32x4*)p;
      f32x4 s1 = *(const f32x4*)(p + 16);
#pragma unroll
      for (int j = 0; j < 4; ++j) {
        _Float16 h0 = (_Float16)s0[j];
        Ahi[mt][j] = h0;
        Alo[mt][j] = (_Float16)(s0[j] - (float)h0);
        _Float16 h1 = (_Float16)s1[j];
        Ahi[mt][4 + j] = h1;
        Alo[mt][4 + j] = (_Float16)(s1[j] - (float)h1);
      }
    }
    const int kb = kc * 32 + q * 8;
#pragma unroll
    for (int nt = 0; nt < 4; ++nt) {
      half8 bhi = *(const half8*)(WThi + (nt * 16 + l16) * 136 + kb);
      half8 blo = *(const half8*)(WTlo + (nt * 16 + l16) * 136 + kb);
#pragma unroll
      for (int mt = 0; mt < 2; ++mt) {
        acc[mt][nt] = __builtin_amdgcn_mfma_f32_16x16x32_f16(Alo[mt], bhi, acc[mt][nt], 0, 0, 0);
        acc[mt][nt] = __builtin_amdgcn_mfma_f32_16x16x32_f16(Ahi[mt], blo, acc[mt][nt], 0, 0, 0);
        acc[mt][nt] = __builtin_amdgcn_mfma_f32_16x16x32_f16(Ahi[mt], bhi, acc[mt][nt], 0, 0, 0);
      }
    }
  }

  float bv[4];
#pragma unroll
  for (int nt = 0; nt < 4; ++nt) bv[nt] = bp[nt * 16 + l16];
  __syncthreads();  // done with W LDS
#pragma unroll
  for (int mt = 0; mt < 2; ++mt) {
#pragma unroll
    for (int reg = 0; reg < 4; ++reg) {
      int row = wave * 32 + mt * 16 + q * 4 + reg;
      float* yr = Yl + row * 68;
#pragma unroll
      for (int nt = 0; nt < 4; ++nt) yr[nt * 16 + l16] = acc[mt][nt][reg] + bv[nt];
    }
  }
  __syncthreads();
  for (int f = t; f < 128 * 16; f += 256) {
    int row = f >> 4, c4 = f & 15;
    int gr = blockRow0 + row;
    if (gr < nodesTotal) {
      f32x4 y = *(const f32x4*)(Yl + row * 68 + c4 * 4);
      *(f32x4*)(Out + (size_t)gr * ODIM + c4 * 4) = y;
    }
  }
}

// ---------------------------------------------------------------------------
extern "C" void kernel_launch(void* const* d_in, const int* in_sizes, int n_in,
                              void* d_out, int out_size, void* d_ws, size_t ws_size,
                              hipStream_t stream) {
  const int* grids = (const int*)d_in[0];
  // d_in[1] = edge_index: unused (fixed 30x30 grid + self-loops, analytic coefs)
  const float* Win  = (const float*)d_in[2];
  const float* bin  = (const float*)d_in[3];
  const float* Wg   = (const float*)d_in[4];
  const float* bg   = (const float*)d_in[5];
  const float* gam  = (const float*)d_in[6];
  const float* bet  = (const float*)d_in[7];
  const float* Wout = (const float*)d_in[8];
  const float* bout = (const float*)d_in[9];
  float* Out = (float*)d_out;

  const int Btot = 512;
  // ping-pong buffers: 2 x (chunkB*900*128 f32)
  const size_t perBatchBytes = (size_t)900 * HID * 4 * 2;
  int chunkB = (int)(ws_size / perBatchBytes);
  if (chunkB > Btot) chunkB = Btot;
  if (chunkB < 1) chunkB = 1;
  int nch = (Btot + chunkB - 1) / chunkB;

  float* Xa = (float*)d_ws;
  float* Xb = Xa + (size_t)chunkB * 900 * HID;

  for (int ci = 0; ci < nch; ++ci) {
    int b0 = ci * chunkB;
    int cb = Btot - b0;
    if (cb > chunkB) cb = chunkB;
    int nodes = cb * 900;
    int gb = (nodes + 127) / 128;

    k_encode<<<dim3((nodes * 32 + 255) / 256), dim3(256), 0, stream>>>(
        grids, Win, bin, Xa, b0, nodes);
    float* src = Xa;
    float* dst = Xb;
    for (int l = 0; l < 4; ++l) {
      k_hidden<<<dim3(gb), dim3(256), 0, stream>>>(
          src, dst, Wg + l * HID * HID, bg + l * HID, gam + l * HID,
          bet + l * HID, nodes);
      float* tmp = src; src = dst; dst = tmp;
    }
    // after 4 swaps the final X is back in `src` (== Xa)
    k_head<<<dim3(gb), dim3(256), 0, stream>>>(
        src, Out + (size_t)b0 * 900 * ODIM, Wout, bout, nodes);
  }
}

// Round 4
// 1117.777 us; speedup vs baseline: 2.0152x; 1.0969x over previous
//
#include <hip/hip_runtime.h>

#define HID 128
#define ODIM 64

typedef _Float16 half8 __attribute__((ext_vector_type(8)));
typedef _Float16 half2 __attribute__((ext_vector_type(2)));
typedef float f32x4 __attribute__((ext_vector_type(4)));

// ---------------------------------------------------------------------------
// Encode: x0[n][c] = relu(Win[color][c] + fr*Win[10][c] + fc*Win[11][c] + bin[c])
// ---------------------------------------------------------------------------
__global__ __launch_bounds__(256) void k_encode(
    const int* __restrict__ grids, const float* __restrict__ Win,
    const float* __restrict__ binp, float* __restrict__ X, int b0, int nodes) {
  int t = blockIdx.x * 256 + threadIdx.x;
  if (t >= nodes * 32) return;
  int node = t >> 5;
  int i = t & 31;
  int n = node % 900;
  int b = node / 900;
  int r = n / 30, c = n - r * 30;
  int color = grids[(b0 + b) * 900 + n];
  float fr = (float)r / 29.0f, fc = (float)c / 29.0f;
  f32x4 wc = ((const f32x4*)(Win + color * HID))[i];
  f32x4 wr = ((const f32x4*)(Win + 10 * HID))[i];
  f32x4 wl = ((const f32x4*)(Win + 11 * HID))[i];
  f32x4 bb = ((const f32x4*)binp)[i];
  f32x4 v = wc + fr * wr + fc * wl + bb;
#pragma unroll
  for (int j = 0; j < 4; ++j) v[j] = fmaxf(v[j], 0.0f);
  ((f32x4*)(X + (size_t)node * HID))[i] = v;
}

// ---------------------------------------------------------------------------
// Fused GCN layer: Xout = relu(LN((A·Xin)@W + bg)) + Xin
//
// v2: all global reads coalesced via per-K-chunk LDS staging.
//  - X tile (128 rows + 30-row halo each side, 32 ch) staged with f32x4 coop
//    loads into Xt[188][36] (stride 36 dwords -> 16B-aligned rows, <=2-way
//    bank alias = free). The 5-point stencil reads LDS, not scattered global.
//  - W K-chunk (32x128) split to f16 hi/lo, transposed into WT[n][40] planes.
//    LDS total 46.4 KB -> 3 blocks/CU (vs 69.6 KB / 2 blocks in v1).
//  - f16x3-split MFMA products (hi*hi + hi*lo + lo*hi), fp32 accumulate.
//  - Epilogue: bias + LN (row lives in a 16-lane group in C/D layout ->
//    shuffle reduce), relu, residual re-read (L2-hot) + direct store
//    (4x64B segments per inst).
// ---------------------------------------------------------------------------
__global__ __launch_bounds__(256, 3) void k_hidden(
    const float* __restrict__ Xin, float* __restrict__ Xout,
    const float* __restrict__ W, const float* __restrict__ bgp,
    const float* __restrict__ gamp, const float* __restrict__ betp,
    int nodesTotal) {
  constexpr int XTS = 36;    // Xt row stride in dwords
  constexpr int XROWS = 188; // 128 + 2*30 halo
  __shared__ __attribute__((aligned(16))) float Xt[XROWS * XTS];    // 27072 B
  __shared__ __attribute__((aligned(16))) _Float16 WThi[128 * 40];  // 10240 B
  __shared__ __attribute__((aligned(16))) _Float16 WTlo[128 * 40];  // 10240 B

  const int t = threadIdx.x;
  const int lane = t & 63;
  const int wave = t >> 6;
  const int q = lane >> 4, l16 = lane & 15;
  const int blockRow0 = blockIdx.x * 128;
  const int waveRow0 = blockRow0 + wave * 32;

  // per-M-tile stencil LDS row offsets (dwords) + symmetric-norm weights.
  // local(x) = x - blockRow0 + 30; all 5 neighbors land in [0,188) by
  // construction; invalid neighbors get weight 0 (their staged data is
  // clamped-but-finite, 0*finite = 0).
  int roff[2][5];
  float wts[2][5];
#pragma unroll
  for (int mt = 0; mt < 2; ++mt) {
    int nd = waveRow0 + mt * 16 + l16;
    if (nd > nodesTotal - 1) nd = nodesTotal - 1;
    int n = nd % 900;
    int r = n / 30, c = n - r * 30;
    int loc = nd - blockRow0 + 30;
    float dc = rsqrtf((float)(1 + (r > 0) + (r < 29) + (c > 0) + (c < 29)));
    roff[mt][0] = loc * XTS;
    wts[mt][0] = dc * dc;
    roff[mt][1] = (loc - 30) * XTS;
    wts[mt][1] = (r > 0) ? dc * rsqrtf((float)(2 + (r > 1) + (c > 0) + (c < 29))) : 0.f;
    roff[mt][2] = (loc + 30) * XTS;
    wts[mt][2] = (r < 29) ? dc * rsqrtf((float)(2 + (r < 28) + (c > 0) + (c < 29))) : 0.f;
    roff[mt][3] = (loc - 1) * XTS;
    wts[mt][3] = (c > 0) ? dc * rsqrtf((float)(2 + (r > 0) + (r < 29) + (c > 1))) : 0.f;
    roff[mt][4] = (loc + 1) * XTS;
    wts[mt][4] = (c < 29) ? dc * rsqrtf((float)(2 + (r > 0) + (r < 29) + (c < 28))) : 0.f;
  }

  f32x4 acc[2][8];
#pragma unroll
  for (int mt = 0; mt < 2; ++mt)
#pragma unroll
    for (int nt = 0; nt < 8; ++nt) acc[mt][nt] = (f32x4){0.f, 0.f, 0.f, 0.f};

  for (int kc = 0; kc < 4; ++kc) {
    __syncthreads();  // previous iteration's LDS fully consumed
    // ---- stage X tile (coalesced f32x4), rows clamped into [0, nodesTotal)
    for (int f = t; f < XROWS * 8; f += 256) {
      int row = f >> 3, v = f & 7;
      int gr = blockRow0 - 30 + row;
      gr = gr < 0 ? 0 : (gr > nodesTotal - 1 ? nodesTotal - 1 : gr);
      *(f32x4*)(Xt + row * XTS + v * 4) =
          *(const f32x4*)(Xin + (size_t)gr * HID + kc * 32 + v * 4);
    }
    // ---- stage W K-chunk: split f16 hi/lo, transpose to WT[n][k] (stride 40)
    for (int f = t; f < 2048; f += 256) {
      int n = f & 127, kp = f >> 7;  // kp in [0,16): two consecutive k per thread
      const float* wp = W + (size_t)(kc * 32 + kp * 2) * HID + n;
      float w0 = wp[0], w1 = wp[HID];
      _Float16 h0 = (_Float16)w0, h1 = (_Float16)w1;
      half2 hh = {h0, h1};
      half2 ll = {(_Float16)(w0 - (float)h0), (_Float16)(w1 - (float)h1)};
      *(half2*)(WThi + n * 40 + kp * 2) = hh;
      *(half2*)(WTlo + n * 40 + kp * 2) = ll;
    }
    __syncthreads();

    // ---- A fragments: 5-point stencil from LDS, split f16 hi/lo
    half8 Ahi[2], Alo[2];
#pragma unroll
    for (int mt = 0; mt < 2; ++mt) {
      const float* x0 = Xt + roff[mt][0] + q * 8;
      f32x4 s0 = wts[mt][0] * (*(const f32x4*)x0);
      f32x4 s1 = wts[mt][0] * (*(const f32x4*)(x0 + 4));
#pragma unroll
      for (int e = 1; e < 5; ++e) {
        const float* xp = Xt + roff[mt][e] + q * 8;
        s0 += wts[mt][e] * (*(const f32x4*)xp);
        s1 += wts[mt][e] * (*(const f32x4*)(xp + 4));
      }
#pragma unroll
      for (int j = 0; j < 4; ++j) {
        _Float16 h0 = (_Float16)s0[j];
        Ahi[mt][j] = h0;
        Alo[mt][j] = (_Float16)(s0[j] - (float)h0);
        _Float16 h1 = (_Float16)s1[j];
        Ahi[mt][4 + j] = h1;
        Alo[mt][4 + j] = (_Float16)(s1[j] - (float)h1);
      }
    }
    // ---- B fragments + MFMA
    const int kb = q * 8;
#pragma unroll
    for (int nt = 0; nt < 8; ++nt) {
      half8 bhi = *(const half8*)(WThi + (nt * 16 + l16) * 40 + kb);
      half8 blo = *(const half8*)(WTlo + (nt * 16 + l16) * 40 + kb);
#pragma unroll
      for (int mt = 0; mt < 2; ++mt) {
        acc[mt][nt] = __builtin_amdgcn_mfma_f32_16x16x32_f16(Alo[mt], bhi, acc[mt][nt], 0, 0, 0);
        acc[mt][nt] = __builtin_amdgcn_mfma_f32_16x16x32_f16(Ahi[mt], blo, acc[mt][nt], 0, 0, 0);
        acc[mt][nt] = __builtin_amdgcn_mfma_f32_16x16x32_f16(Ahi[mt], bhi, acc[mt][nt], 0, 0, 0);
      }
    }
  }

  // ---- epilogue: bias + LN + relu + residual, direct store from C/D layout
  float bgv[8], gv[8], btv[8];
#pragma unroll
  for (int nt = 0; nt < 8; ++nt) {
    int cl = nt * 16 + l16;
    bgv[nt] = bgp[cl];
    gv[nt] = gamp[cl];
    btv[nt] = betp[cl];
  }
#pragma unroll
  for (int mt = 0; mt < 2; ++mt) {
#pragma unroll
    for (int reg = 0; reg < 4; ++reg) {
      float rs = 0.f;
#pragma unroll
      for (int nt = 0; nt < 8; ++nt) {
        acc[mt][nt][reg] += bgv[nt];
        rs += acc[mt][nt][reg];
      }
      rs += __shfl_xor(rs, 1, 64);
      rs += __shfl_xor(rs, 2, 64);
      rs += __shfl_xor(rs, 4, 64);
      rs += __shfl_xor(rs, 8, 64);
      float mean = rs * (1.f / 128.f);
      float ss = 0.f;
#pragma unroll
      for (int nt = 0; nt < 8; ++nt) {
        float d = acc[mt][nt][reg] - mean;
        ss += d * d;
      }
      ss += __shfl_xor(ss, 1, 64);
      ss += __shfl_xor(ss, 2, 64);
      ss += __shfl_xor(ss, 4, 64);
      ss += __shfl_xor(ss, 8, 64);
      float rsd = rsqrtf(ss * (1.f / 128.f) + 1e-5f);
      int row = waveRow0 + mt * 16 + q * 4 + reg;  // uniform across the 16-lane group
      if (row < nodesTotal) {
        const float* xr = Xin + (size_t)row * HID;
        float* xo = Xout + (size_t)row * HID;
#pragma unroll
        for (int nt = 0; nt < 8; ++nt) {
          int col = nt * 16 + l16;
          float y = fmaxf((acc[mt][nt][reg] - mean) * rsd * gv[nt] + btv[nt], 0.f);
          xo[col] = y + xr[col];
        }
      }
    }
  }
}

// ---------------------------------------------------------------------------
// Head: Out = Xin @ Wout + bout (same staged structure, no stencil/LN/residual)
// ---------------------------------------------------------------------------
__global__ __launch_bounds__(256, 4) void k_head(
    const float* __restrict__ Xin, float* __restrict__ Out,
    const float* __restrict__ W, const float* __restrict__ bp, int nodesTotal) {
  constexpr int XTS = 36;
  __shared__ __attribute__((aligned(16))) float Xt[128 * XTS];     // 18432 B
  __shared__ __attribute__((aligned(16))) _Float16 WThi[64 * 40];  // 5120 B
  __shared__ __attribute__((aligned(16))) _Float16 WTlo[64 * 40];  // 5120 B

  const int t = threadIdx.x;
  const int lane = t & 63;
  const int wave = t >> 6;
  const int q = lane >> 4, l16 = lane & 15;
  const int blockRow0 = blockIdx.x * 128;
  const int waveRow0 = blockRow0 + wave * 32;

  int roff[2];
#pragma unroll
  for (int mt = 0; mt < 2; ++mt) {
    int nd = waveRow0 + mt * 16 + l16;
    if (nd > nodesTotal - 1) nd = nodesTotal - 1;
    roff[mt] = (nd - blockRow0) * XTS;
  }

  f32x4 acc[2][4];
#pragma unroll
  for (int mt = 0; mt < 2; ++mt)
#pragma unroll
    for (int nt = 0; nt < 4; ++nt) acc[mt][nt] = (f32x4){0.f, 0.f, 0.f, 0.f};

  for (int kc = 0; kc < 4; ++kc) {
    __syncthreads();
    for (int f = t; f < 128 * 8; f += 256) {
      int row = f >> 3, v = f & 7;
      int gr = blockRow0 + row;
      if (gr > nodesTotal - 1) gr = nodesTotal - 1;
      *(f32x4*)(Xt + row * XTS + v * 4) =
          *(const f32x4*)(Xin + (size_t)gr * HID + kc * 32 + v * 4);
    }
    for (int f = t; f < 1024; f += 256) {
      int n = f & 63, kp = f >> 6;  // kp in [0,16)
      const float* wp = W + (size_t)(kc * 32 + kp * 2) * ODIM + n;
      float w0 = wp[0], w1 = wp[ODIM];
      _Float16 h0 = (_Float16)w0, h1 = (_Float16)w1;
      half2 hh = {h0, h1};
      half2 ll = {(_Float16)(w0 - (float)h0), (_Float16)(w1 - (float)h1)};
      *(half2*)(WThi + n * 40 + kp * 2) = hh;
      *(half2*)(WTlo + n * 40 + kp * 2) = ll;
    }
    __syncthreads();

    half8 Ahi[2], Alo[2];
#pragma unroll
    for (int mt = 0; mt < 2; ++mt) {
      const float* xp = Xt + roff[mt] + q * 8;
      f32x4 s0 = *(const f32x4*)xp;
      f32x4 s1 = *(const f32x4*)(xp + 4);
#pragma unroll
      for (int j = 0; j < 4; ++j) {
        _Float16 h0 = (_Float16)s0[j];
        Ahi[mt][j] = h0;
        Alo[mt][j] = (_Float16)(s0[j] - (float)h0);
        _Float16 h1 = (_Float16)s1[j];
        Ahi[mt][4 + j] = h1;
        Alo[mt][4 + j] = (_Float16)(s1[j] - (float)h1);
      }
    }
    const int kb = q * 8;
#pragma unroll
    for (int nt = 0; nt < 4; ++nt) {
      half8 bhi = *(const half8*)(WThi + (nt * 16 + l16) * 40 + kb);
      half8 blo = *(const half8*)(WTlo + (nt * 16 + l16) * 40 + kb);
#pragma unroll
      for (int mt = 0; mt < 2; ++mt) {
        acc[mt][nt] = __builtin_amdgcn_mfma_f32_16x16x32_f16(Alo[mt], bhi, acc[mt][nt], 0, 0, 0);
        acc[mt][nt] = __builtin_amdgcn_mfma_f32_16x16x32_f16(Ahi[mt], blo, acc[mt][nt], 0, 0, 0);
        acc[mt][nt] = __builtin_amdgcn_mfma_f32_16x16x32_f16(Ahi[mt], bhi, acc[mt][nt], 0, 0, 0);
      }
    }
  }

  float bv[4];
#pragma unroll
  for (int nt = 0; nt < 4; ++nt) bv[nt] = bp[nt * 16 + l16];
#pragma unroll
  for (int mt = 0; mt < 2; ++mt) {
#pragma unroll
    for (int reg = 0; reg < 4; ++reg) {
      int row = waveRow0 + mt * 16 + q * 4 + reg;
      if (row < nodesTotal) {
        float* op = Out + (size_t)row * ODIM;
#pragma unroll
        for (int nt = 0; nt < 4; ++nt)
          op[nt * 16 + l16] = acc[mt][nt][reg] + bv[nt];
      }
    }
  }
}

// ---------------------------------------------------------------------------
extern "C" void kernel_launch(void* const* d_in, const int* in_sizes, int n_in,
                              void* d_out, int out_size, void* d_ws, size_t ws_size,
                              hipStream_t stream) {
  const int* grids = (const int*)d_in[0];
  // d_in[1] = edge_index: unused (fixed 30x30 grid + self-loops, analytic coefs)
  const float* Win  = (const float*)d_in[2];
  const float* bin  = (const float*)d_in[3];
  const float* Wg   = (const float*)d_in[4];
  const float* bg   = (const float*)d_in[5];
  const float* gam  = (const float*)d_in[6];
  const float* bet  = (const float*)d_in[7];
  const float* Wout = (const float*)d_in[8];
  const float* bout = (const float*)d_in[9];
  float* Out = (float*)d_out;

  const int Btot = 512;
  const size_t perBatchBytes = (size_t)900 * HID * 4 * 2;  // ping-pong X buffers
  int chunkB = (int)(ws_size / perBatchBytes);
  if (chunkB > Btot) chunkB = Btot;
  if (chunkB < 1) chunkB = 1;
  int nch = (Btot + chunkB - 1) / chunkB;

  float* Xa = (float*)d_ws;
  float* Xb = Xa + (size_t)chunkB * 900 * HID;

  for (int ci = 0; ci < nch; ++ci) {
    int b0 = ci * chunkB;
    int cb = Btot - b0;
    if (cb > chunkB) cb = chunkB;
    int nodes = cb * 900;
    int gb = (nodes + 127) / 128;

    k_encode<<<dim3((nodes * 32 + 255) / 256), dim3(256), 0, stream>>>(
        grids, Win, bin, Xa, b0, nodes);
    float* src = Xa;
    float* dst = Xb;
    for (int l = 0; l < 4; ++l) {
      k_hidden<<<dim3(gb), dim3(256), 0, stream>>>(
          src, dst, Wg + l * HID * HID, bg + l * HID, gam + l * HID,
          bet + l * HID, nodes);
      float* tmp = src; src = dst; dst = tmp;
    }
    // after 4 swaps the final X is back in Xa
    k_head<<<dim3(gb), dim3(256), 0, stream>>>(
        src, Out + (size_t)b0 * 900 * ODIM, Wout, bout, nodes);
  }
}